// Round 1
// baseline (18553.287 us; speedup 1.0000x reference)
//
#include <hip/hip_runtime.h>

// RITS recurrence on MI355X.
// Design: 64 persistent blocks x 1024 threads (16 waves). Each block owns 16
// batch rows for all 512 timesteps (batch rows are independent -> no grid
// sync). All weights converted to bf16 once (prep kernel -> d_ws) and held
// REGISTER-RESIDENT as MFMA B-fragments (~336 VGPR/wave); activations flow
// through LDS. fp32 cell/hidden state in registers; m==1 passthrough of x is
// exact fp32.

#define T_STEPS 512
#define DD 128
#define HH 256

typedef __bf16 bf16_t;
typedef bf16_t bf8 __attribute__((ext_vector_type(8)));
typedef float f32x4 __attribute__((ext_vector_type(4)));

__device__ __forceinline__ float sigmoidf_(float x) { return 1.f / (1.f + __expf(-x)); }

// ws layout (bf16 elements):
//      0: Wd_h [256][128]
//  32768: Wd_x [128][128]
//  49152: Wh   [128][256]
//  81920: Wf   [128][128]
//  98304: Wc   [128][256]
// 131072: W6   [1024][512]  = [Wih | Whh] fused along K
// total 655360 elems = 1.31 MB
__global__ void prep_weights(const float* __restrict__ Wd_h, const float* __restrict__ Wd_x,
                             const float* __restrict__ Wh, const float* __restrict__ Wf,
                             const float* __restrict__ Wc, const float* __restrict__ Wih,
                             const float* __restrict__ Whh, bf16_t* __restrict__ ws) {
  int i = blockIdx.x * 256 + threadIdx.x;  // grid sized exactly 655360
  float v;
  if (i < 32768)        v = Wd_h[i];
  else if (i < 49152)   v = Wd_x[i - 32768];
  else if (i < 81920)   v = Wh[i - 49152];
  else if (i < 98304)   v = Wf[i - 81920];
  else if (i < 131072)  v = Wc[i - 98304];
  else {
    int j = i - 131072; int n = j >> 9; int k = j & 511;
    v = (k < 256) ? Wih[n * 256 + k] : Whh[n * 256 + k - 256];
  }
  ws[i] = (bf16_t)v;
}

__global__ __launch_bounds__(1024, 4) void rits_main(
    const float* __restrict__ values, const int* __restrict__ masks,
    const float* __restrict__ deltas,
    const float* __restrict__ bd_h, const float* __restrict__ bd_x,
    const float* __restrict__ bh_v, const float* __restrict__ bf_v,
    const float* __restrict__ bc_v,
    const float* __restrict__ bih, const float* __restrict__ bhh,
    const float* __restrict__ Wo, const float* __restrict__ bo,
    const bf16_t* __restrict__ ws, float* __restrict__ out) {
  // activation staging; rows padded +8 bf16 (+4 f32) to break bank strides
  __shared__ bf16_t sD[16][136];    // deltas_t  bf16
  __shared__ bf16_t sM[16][136];    // mask_t    bf16 (0/1 exact)
  __shared__ float  sX[16][132];    // values_t  f32 (exact passthrough)
  __shared__ bf16_t sHt[16][264];   // h~ = h*gamma_h, bf16 (A of x_h & gates)
  __shared__ bf16_t sGx[16][136];   // gamma_x bf16 (A of alpha)
  __shared__ bf16_t sXh[16][136];   // x_h bf16
  __shared__ bf16_t sXc[16][136];   // x_c bf16 (A of z_h)
  __shared__ bf16_t sCc[16][136];   // c_c bf16 (A of gates)

  const int tid  = threadIdx.x;
  const int w    = tid >> 6;        // wave 0..15
  const int lane = tid & 63;
  const int l15  = lane & 15;
  const int quad = lane >> 4;
  const int rb   = blockIdx.x * 16; // global batch-row base

  // ---- register-resident weight fragments (B-operand: W[n][k], n=l15, k=quad*8+j) ----
  bf8 Wgh[4];      // Wd_h tile w                (all waves)
  bf8 Wa[4];       // w<8: Wd_x tile w ; w>=8: Wf tile w-8
  bf8 Wb[8];       // w<8: Wh   tile w ; w>=8: Wc tile w-8
  bf8 W6[4][16];   // gates: n-tiles {w,w+16,w+32,w+48} (i,f,g,o aligned), k 0..15
#pragma unroll
  for (int kc = 0; kc < 4; kc++)
    Wgh[kc] = *(const bf8*)(ws + (16 * w + l15) * 128 + kc * 32 + quad * 8);
  if (w < 8) {
#pragma unroll
    for (int kc = 0; kc < 4; kc++)
      Wa[kc] = *(const bf8*)(ws + 32768 + (16 * w + l15) * 128 + kc * 32 + quad * 8);
#pragma unroll
    for (int kc = 0; kc < 8; kc++)
      Wb[kc] = *(const bf8*)(ws + 49152 + (16 * w + l15) * 256 + kc * 32 + quad * 8);
  } else {
    const int wt = w - 8;
#pragma unroll
    for (int kc = 0; kc < 4; kc++)
      Wa[kc] = *(const bf8*)(ws + 81920 + (16 * wt + l15) * 128 + kc * 32 + quad * 8);
#pragma unroll
    for (int kc = 0; kc < 8; kc++)
      Wb[kc] = *(const bf8*)(ws + 98304 + (16 * wt + l15) * 256 + kc * 32 + quad * 8);
  }
#pragma unroll
  for (int q = 0; q < 4; q++)
#pragma unroll
    for (int kc = 0; kc < 16; kc++)
      W6[q][kc] = *(const bf8*)(ws + 131072 + (16 * (w + 16 * q) + l15) * 512 + kc * 32 + quad * 8);

  // biases (per-owner columns)
  const float b_gh = bd_h[16 * w + l15];
  float b_a, b_b;
  if (w < 8) { b_a = bd_x[16 * w + l15]; b_b = bh_v[16 * w + l15]; }
  else       { const int wt = w - 8; b_a = bf_v[16 * wt + l15]; b_b = bc_v[16 * wt + l15]; }
  float b6[4];
#pragma unroll
  for (int q = 0; q < 4; q++) {
    const int col = 256 * q + 16 * w + l15;
    b6[q] = bih[col] + bhh[col];
  }

  // fp32 recurrent state: rows quad*4+r, col 16w+l15 (same thread owns
  // gamma_h, LSTM gates, and h for these coordinates -> no LDS round-trip)
  float hreg[4] = {0.f, 0.f, 0.f, 0.f};
  float creg[4] = {0.f, 0.f, 0.f, 0.f};

  float* __restrict__ imps = out + 2048;  // output 1 after y_h [1024,2]

  for (int t = 0; t < T_STEPS; t++) {
    __syncthreads();  // prev-step P4 readers done before restaging
    // P0: stage inputs for step t
#pragma unroll
    for (int e = tid; e < 2048; e += 1024) {
      const int r = e >> 7, c = e & 127;
      const long g = (long)(rb + r) * (T_STEPS * DD) + (long)t * DD + c;
      sD[r][c] = (bf16_t)deltas[g];
      sM[r][c] = (bf16_t)(float)masks[g];
      sX[r][c] = values[g];
    }
    __syncthreads();
    // P1: gamma_h (all waves) -> h~ ; gamma_x (waves 0-7)
    {
      f32x4 acc = {0.f, 0.f, 0.f, 0.f};
#pragma unroll
      for (int kc = 0; kc < 4; kc++) {
        bf8 a = *(const bf8*)(&sD[l15][kc * 32 + quad * 8]);
        acc = __builtin_amdgcn_mfma_f32_16x16x32_bf16(a, Wgh[kc], acc, 0, 0, 0);
      }
#pragma unroll
      for (int r = 0; r < 4; r++) {
        const float g = __expf(-fmaxf(acc[r] + b_gh, 0.f));
        sHt[quad * 4 + r][16 * w + l15] = (bf16_t)(hreg[r] * g);
      }
    }
    if (w < 8) {
      f32x4 acc = {0.f, 0.f, 0.f, 0.f};
#pragma unroll
      for (int kc = 0; kc < 4; kc++) {
        bf8 a = *(const bf8*)(&sD[l15][kc * 32 + quad * 8]);
        acc = __builtin_amdgcn_mfma_f32_16x16x32_bf16(a, Wa[kc], acc, 0, 0, 0);
      }
#pragma unroll
      for (int r = 0; r < 4; r++)
        sGx[quad * 4 + r][16 * w + l15] = (bf16_t)__expf(-fmaxf(acc[r] + b_a, 0.f));
    }
    __syncthreads();
    // P2: x_h (waves 0-7, Wh over h~) || alpha (waves 8-15, Wc over [gx|m])
    float alphav[4];
    if (w < 8) {
      f32x4 acc = {0.f, 0.f, 0.f, 0.f};
#pragma unroll
      for (int kc = 0; kc < 8; kc++) {
        bf8 a = *(const bf8*)(&sHt[l15][kc * 32 + quad * 8]);
        acc = __builtin_amdgcn_mfma_f32_16x16x32_bf16(a, Wb[kc], acc, 0, 0, 0);
      }
#pragma unroll
      for (int r = 0; r < 4; r++) {
        const int row = quad * 4 + r, col = 16 * w + l15;
        const float xh = acc[r] + b_b;
        const float m = (float)sM[row][col];
        sXh[row][col] = (bf16_t)xh;
        sXc[row][col] = (bf16_t)(m * sX[row][col] + (1.f - m) * xh);
      }
    } else {
      f32x4 acc = {0.f, 0.f, 0.f, 0.f};
#pragma unroll
      for (int kc = 0; kc < 8; kc++) {
        bf8 a = (kc < 4) ? *(const bf8*)(&sGx[l15][kc * 32 + quad * 8])
                         : *(const bf8*)(&sM[l15][(kc - 4) * 32 + quad * 8]);
        acc = __builtin_amdgcn_mfma_f32_16x16x32_bf16(a, Wb[kc], acc, 0, 0, 0);
      }
#pragma unroll
      for (int r = 0; r < 4; r++) alphav[r] = acc[r] + b_b;
    }
    __syncthreads();
    // P3: z_h (waves 8-15, Wf over x_c) -> c_h, c_c, imputation store
    if (w >= 8) {
      f32x4 acc = {0.f, 0.f, 0.f, 0.f};
#pragma unroll
      for (int kc = 0; kc < 4; kc++) {
        bf8 a = *(const bf8*)(&sXc[l15][kc * 32 + quad * 8]);
        acc = __builtin_amdgcn_mfma_f32_16x16x32_bf16(a, Wa[kc], acc, 0, 0, 0);
      }
      const int wt = w - 8;
#pragma unroll
      for (int r = 0; r < 4; r++) {
        const int row = quad * 4 + r, col = 16 * wt + l15;
        const float zh = acc[r] + b_a;
        const float al = alphav[r];
        const float xh = (float)sXh[row][col];
        const float ch = al * zh + (1.f - al) * xh;
        const float m = (float)sM[row][col];
        const float cc = m * sX[row][col] + (1.f - m) * ch;
        sCc[row][col] = (bf16_t)cc;
        imps[(long)(rb + row) * (T_STEPS * DD) + (long)t * DD + col] = cc;
      }
    }
    __syncthreads();
    // P4: gates = [c_c|m]@Wih^T + h~@Whh^T (+biases), LSTM update (wave-local)
    {
      f32x4 acc[4] = {{0.f,0.f,0.f,0.f},{0.f,0.f,0.f,0.f},{0.f,0.f,0.f,0.f},{0.f,0.f,0.f,0.f}};
#pragma unroll
      for (int kc = 0; kc < 16; kc++) {
        bf8 a;
        if (kc < 4)      a = *(const bf8*)(&sCc[l15][kc * 32 + quad * 8]);
        else if (kc < 8) a = *(const bf8*)(&sM[l15][(kc - 4) * 32 + quad * 8]);
        else             a = *(const bf8*)(&sHt[l15][(kc - 8) * 32 + quad * 8]);
#pragma unroll
        for (int q = 0; q < 4; q++)
          acc[q] = __builtin_amdgcn_mfma_f32_16x16x32_bf16(a, W6[q][kc], acc[q], 0, 0, 0);
      }
#pragma unroll
      for (int r = 0; r < 4; r++) {
        const float gi = sigmoidf_(acc[0][r] + b6[0]);
        const float gf = sigmoidf_(acc[1][r] + b6[1]);
        const float gg = tanhf(acc[2][r] + b6[2]);
        const float go = sigmoidf_(acc[3][r] + b6[3]);
        creg[r] = gf * creg[r] + gi * gg;
        hreg[r] = go * tanhf(creg[r]);
      }
    }
  }

  // final y_h = h @ Wo^T + bo   (reuse sHt to gather full h)
  __syncthreads();
#pragma unroll
  for (int r = 0; r < 4; r++)
    sHt[quad * 4 + r][16 * w + l15] = (bf16_t)hreg[r];
  __syncthreads();
  if (tid < 32) {
    const int r = tid >> 1, c = tid & 1;
    float acc = bo[c];
    for (int k = 0; k < 256; k++) acc += (float)sHt[r][k] * Wo[c * 256 + k];
    out[(rb + r) * 2 + c] = acc;
  }
}

extern "C" void kernel_launch(void* const* d_in, const int* in_sizes, int n_in,
                              void* d_out, int out_size, void* d_ws, size_t ws_size,
                              hipStream_t stream) {
  const float* values = (const float*)d_in[0];
  const int*   masks  = (const int*)d_in[1];
  const float* deltas = (const float*)d_in[2];
  const float* Wd_h = (const float*)d_in[3];
  const float* bd_h = (const float*)d_in[4];
  const float* Wd_x = (const float*)d_in[5];
  const float* bd_x = (const float*)d_in[6];
  const float* Wh   = (const float*)d_in[7];
  const float* bh   = (const float*)d_in[8];
  const float* Wf   = (const float*)d_in[9];
  const float* bf   = (const float*)d_in[10];
  const float* Wc   = (const float*)d_in[11];
  const float* bc   = (const float*)d_in[12];
  const float* Wih  = (const float*)d_in[13];
  const float* bih  = (const float*)d_in[14];
  const float* Whh  = (const float*)d_in[15];
  const float* bhh  = (const float*)d_in[16];
  const float* Wo   = (const float*)d_in[17];
  const float* bo   = (const float*)d_in[18];
  bf16_t* ws = (bf16_t*)d_ws;
  float* out = (float*)d_out;

  prep_weights<<<2560, 256, 0, stream>>>(Wd_h, Wd_x, Wh, Wf, Wc, Wih, Whh, ws);
  rits_main<<<64, 1024, 0, stream>>>(values, masks, deltas, bd_h, bd_x, bh, bf, bc,
                                     bih, bhh, Wo, bo, ws, out);
}